// Round 2
// baseline (4555.358 us; speedup 1.0000x reference)
//
#include <hip/hip_runtime.h>

#define N_USERS 100000
#define N_ITEMS 50000
#define N_NODES 150000
#define EMBED   64
#define NNZV    4000000
#define BATCH   4096

// ---- col-blocked bucket layout -------------------------------------------
// bucket = row >> 7  : 128 rows/bucket, 1172 buckets (LDS acc = 32 KB -> 5 blk/CU,
//                      grid 1172 <= 1280 resident -> zero tail)
// colblk = col >> 13 : 8192 cols/blk = 2 MB of embeddings -> fits 4 MB XCD L2
// segment = bucket*19 + colblk : edges sorted bucket-major, colblk-minor, so a
// block's edge span is contiguous and all blocks sweep col windows in lockstep.
#define BROWS   128
#define NBKT    1172               // ceil(150000/128)
#define NCB     19                 // ceil(150000/8192)
#define NSEG    (NBKT * NCB)       // 22268 (even)
#define CAP2    320                // staging cap/segment: mean 186, ~9.8 sigma
#define EPB     8192               // edges per k_part block

// ---------------- Phase A: partition edges into segments ---------------------
// One pass replaces old parta+partb: record goes DIRECTLY to its padded segment
// slot. Packed u16 LDS counters double as count (pass 1) then global-base+rank
// cursor (pass 2): sweep stores the globally-reserved base into the same slot,
// so pass-2 atomicAdd returns base+rank in one op. No partb row-sort needed.
// Regular (non-nt) stores on staging: scattered 8B writes need L2 write-merge
// (R11 lesson). Record: low32 = (r&127)<<18 | col, high32 = val bits.
__global__ __launch_bounds__(512) void k_part(
        const int* __restrict__ row, const int* __restrict__ col,
        const float* __restrict__ vals, int* __restrict__ gcnt,
        unsigned long long* __restrict__ staging) {
    __shared__ unsigned int cntp[NSEG / 2];          // 44.5 KB -> 3 blocks/CU
    int tid = threadIdx.x;
    for (int i = tid; i < NSEG / 2; i += 512) cntp[i] = 0u;
    __syncthreads();
    int e0 = blockIdx.x * EPB;
    int er[16], ec[16];
    #pragma unroll
    for (int k = 0; k < 16; k++) {
        int e = e0 + k * 512 + tid;
        er[k] = 0; ec[k] = 0;
        if (e < NNZV) {
            er[k] = row[e];
            ec[k] = col[e];
            int s = (er[k] >> 7) * NCB + (ec[k] >> 13);
            atomicAdd(&cntp[s >> 1], 1u << ((s & 1) * 16));
        }
    }
    __syncthreads();
    // reserve global ranges; overwrite packed counts with packed global bases
    for (int w = tid; w < NSEG / 2; w += 512) {
        unsigned int pc = cntp[w];
        unsigned int c0 = pc & 0xffffu, c1 = pc >> 16;
        unsigned int g0 = c0 ? (unsigned int)atomicAdd(&gcnt[2 * w], (int)c0) : 0u;
        unsigned int g1 = c1 ? (unsigned int)atomicAdd(&gcnt[2 * w + 1], (int)c1) : 0u;
        cntp[w] = g0 | (g1 << 16);
    }
    __syncthreads();
    #pragma unroll
    for (int k = 0; k < 16; k++) {
        int e = e0 + k * 512 + tid;
        if (e < NNZV) {
            int r = er[k], c = ec[k];
            int s = (r >> 7) * NCB + (c >> 13);
            unsigned int old = atomicAdd(&cntp[s >> 1], 1u << ((s & 1) * 16));
            unsigned int idx = (old >> ((s & 1) * 16)) & 0xffffu;   // base+rank
            unsigned long long rec = ((unsigned long long)__float_as_uint(vals[e]) << 32)
                                   | ((unsigned int)(r & (BROWS - 1)) << 18)
                                   | (unsigned int)c;
            staging[(size_t)s * CAP2 + idx] = rec;
        }
    }
}

// ---------------- exclusive scan of segment counts ---------------------------
#define SCAN_T 1024
#define SCAN_C 22          // 1024*22 = 22528 >= NSEG
__global__ __launch_bounds__(SCAN_T) void k_scan(const int* __restrict__ gcnt,
                                                 int* __restrict__ seg_ptr) {
    __shared__ int sh[SCAN_T];
    int t = threadIdx.x;
    int loc[SCAN_C];
    int s = 0;
    #pragma unroll
    for (int i = 0; i < SCAN_C; i++) {
        int idx = t * SCAN_C + i;
        loc[i] = s;
        s += (idx < NSEG) ? gcnt[idx] : 0;
    }
    sh[t] = s;
    __syncthreads();
    for (int off = 1; off < SCAN_T; off <<= 1) {
        int u = (t >= off) ? sh[t - off] : 0;
        __syncthreads();
        sh[t] += u;
        __syncthreads();
    }
    int excl = sh[t] - s;
    #pragma unroll
    for (int i = 0; i < SCAN_C; i++) {
        int idx = t * SCAN_C + i;
        if (idx < NSEG) seg_ptr[idx] = excl + loc[i];
    }
    if (t == SCAN_T - 1) seg_ptr[NSEG] = sh[t];
}

// ---------------- compact padded staging -> dense edges ----------------------
__global__ __launch_bounds__(256) void k_compact(const int* __restrict__ seg_ptr,
        const unsigned long long* __restrict__ staging,
        unsigned long long* __restrict__ edges) {
    for (int s = blockIdx.x; s < NSEG; s += gridDim.x) {
        int st = seg_ptr[s], en = seg_ptr[s + 1];
        const unsigned long long* src = staging + (size_t)s * CAP2;
        for (int i = threadIdx.x; i < en - st; i += 256)
            edges[st + i] = src[i];
    }
}

// ---------------- col-blocked SpMM -------------------------------------------
// Block = 256 thr owns one 128-row bucket; acc[128][64] f32 in LDS (32 KB).
// Wave-per-edge: lane l owns float l of the row -> ds_add_f32 at 2 lanes/bank
// (free). readlane keeps all per-edge broadcasts (col, row, val, addresses) in
// SGPRs/SALU; per-edge VALU is ~1 mul + 1 add. Edges swept in colblk order ->
// gathers stay inside a 2 MB L2-resident window; each XCD streams each colblk
// once instead of random-missing to L3.
__global__ __launch_bounds__(256) void k_bspmm(
        const int* __restrict__ seg_ptr,
        const unsigned long long* __restrict__ edges,
        const float* __restrict__ Eu,      // base for cc <  N_USERS
        const float* __restrict__ Ei_s,    // pre-shifted base for cc >= N_USERS
        float4* __restrict__ Eout4) {
    __shared__ float4 accv[BROWS * 16];    // 32 KB, 16B-aligned
    float* acc = (float*)accv;
    int b = blockIdx.x;
    for (int i = threadIdx.x; i < BROWS * 16; i += 256)
        accv[i] = make_float4(0.f, 0.f, 0.f, 0.f);
    __syncthreads();
    int st = seg_ptr[b * NCB];
    int en = seg_ptr[b * NCB + NCB];       // bucket's edges are contiguous
    int lane = threadIdx.x & 63;
    int w = threadIdx.x >> 6;
    for (int c0 = st + w * 64; c0 < en; c0 += 256) {
        int m = en - c0; if (m > 64) m = 64;
        unsigned long long rec = 0ull;
        if (lane < m) rec = __builtin_nontemporal_load(edges + c0 + lane);
        int key = (int)(unsigned int)rec;
        int vhi = (int)(rec >> 32);
        #pragma unroll 8
        for (int k = 0; k < m; k++) {
            int kk   = __builtin_amdgcn_readlane(key, k);
            float vv = __int_as_float(__builtin_amdgcn_readlane(vhi, k));
            int cc = kk & 0x3FFFF;
            int rl = kk >> 18;
            const float* ep = (cc < N_USERS) ? Eu : Ei_s;   // scalar select
            float ev = ep[(size_t)cc * 64 + lane];
            (void)__hip_atomic_fetch_add(&acc[rl * 64 + lane], vv * ev,
                                         __ATOMIC_RELAXED,
                                         __HIP_MEMORY_SCOPE_WORKGROUP);
        }
    }
    __syncthreads();
    size_t r0 = (size_t)b * BROWS;
    for (int i = threadIdx.x; i < BROWS * 16; i += 256) {
        size_t rr = r0 + (size_t)(i >> 4);
        if (rr < N_NODES) Eout4[rr * 16 + (i & 15)] = accv[i];
    }
}

// ---------------- init gather: out = 0.25 * E0[batch] (virtual concat) -------
__global__ void k_gather_init(const int* __restrict__ bu, const int* __restrict__ bp,
                              const int* __restrict__ bn,
                              const float4* __restrict__ eu4,
                              const float4* __restrict__ ei4s,
                              float4* __restrict__ out) {
    int idx = blockIdx.x * blockDim.x + threadIdx.x;
    if (idx >= 3 * BATCH * 16) return;
    int j = idx >> 4;
    int d = idx & 15;
    int node;
    if (j < BATCH)          node = bu[j];
    else if (j < 2 * BATCH) node = N_USERS + bp[j - BATCH];
    else                    node = N_USERS + bn[j - 2 * BATCH];
    const float4* basep = (node < N_USERS) ? eu4 : ei4s;
    float4 v = basep[node * 16 + d];
    v.x *= 0.25f; v.y *= 0.25f; v.z *= 0.25f; v.w *= 0.25f;
    out[idx] = v;
}

// ---------------- accumulate gather: out += 0.25 * E[batch] ------------------
__global__ void k_gather_acc(const int* __restrict__ bu, const int* __restrict__ bp,
                             const int* __restrict__ bn, const float4* __restrict__ E,
                             float4* __restrict__ out) {
    int idx = blockIdx.x * blockDim.x + threadIdx.x;
    if (idx >= 3 * BATCH * 16) return;
    int j = idx >> 4;
    int d = idx & 15;
    int node;
    if (j < BATCH)          node = bu[j];
    else if (j < 2 * BATCH) node = N_USERS + bp[j - BATCH];
    else                    node = N_USERS + bn[j - 2 * BATCH];
    float4 v = E[node * 16 + d];
    float4 o = out[idx];
    o.x += 0.25f * v.x; o.y += 0.25f * v.y; o.z += 0.25f * v.z; o.w += 0.25f * v.w;
    out[idx] = o;
}

extern "C" void kernel_launch(void* const* d_in, const int* in_sizes, int n_in,
                              void* d_out, int out_size, void* d_ws, size_t ws_size,
                              hipStream_t stream) {
    const int*   bu   = (const int*)d_in[0];
    const int*   bp   = (const int*)d_in[1];
    const int*   bn   = (const int*)d_in[2];
    const float* eu   = (const float*)d_in[3];
    const float* ei   = (const float*)d_in[4];
    const int*   row  = (const int*)d_in[5];
    const int*   col  = (const int*)d_in[6];
    const float* vals = (const float*)d_in[7];
    float* out = (float*)d_out;

    char* p = (char*)d_ws;
    auto alloc = [&](size_t nbytes) {
        void* r = (void*)p;
        p += (nbytes + 255) & ~(size_t)255;
        return r;
    };
    float*              E_a     = (float*)alloc((size_t)N_NODES * EMBED * 4);  // 38.4 MB
    float*              E_b     = (float*)alloc((size_t)N_NODES * EMBED * 4);  // 38.4 MB
    unsigned long long* edges   = (unsigned long long*)alloc((size_t)NNZV * 8);// 32.0 MB
    int*                seg_ptr = (int*)alloc((size_t)(NSEG + 1) * 4);
    int*                gcnt    = (int*)alloc((size_t)NSEG * 4);
    (void)ws_size; (void)n_in; (void)in_sizes; (void)out_size;

    // staging (NSEG*CAP2*8 = 57.0 MB) overlays E_a+E_b (76.8 MB): dead after
    // k_compact, before k_bspmm writes E_a (same stream => ordered).
    unsigned long long* staging = (unsigned long long*)E_a;

    const float4* eu4  = (const float4*)eu;
    const float4* ei4s = (const float4*)ei - (size_t)N_USERS * 16;  // float4 units
    const float*  ei_s = ei - (size_t)N_USERS * 64;                 // float units

    hipMemsetAsync(gcnt, 0, (size_t)NSEG * 4, stream);

    k_part<<<(NNZV + EPB - 1) / EPB, 512, 0, stream>>>(row, col, vals, gcnt, staging);
    k_scan<<<1, SCAN_T, 0, stream>>>(gcnt, seg_ptr);
    k_compact<<<2048, 256, 0, stream>>>(seg_ptr, staging, edges);

    // out = 0.25 * E0[batch]
    k_gather_init<<<(3 * BATCH * 16 + 255) / 256, 256, 0, stream>>>(
        bu, bp, bn, eu4, ei4s, (float4*)out);

    // layer 1: E1 = A * E0 (virtual concat input)
    k_bspmm<<<NBKT, 256, 0, stream>>>(seg_ptr, edges, eu, ei_s, (float4*)E_a);
    k_gather_acc<<<(3 * BATCH * 16 + 255) / 256, 256, 0, stream>>>(
        bu, bp, bn, (const float4*)E_a, (float4*)out);

    // layer 2: E2 = A * E1
    k_bspmm<<<NBKT, 256, 0, stream>>>(seg_ptr, edges, E_a, E_a, (float4*)E_b);
    k_gather_acc<<<(3 * BATCH * 16 + 255) / 256, 256, 0, stream>>>(
        bu, bp, bn, (const float4*)E_b, (float4*)out);

    // layer 3: E3 = A * E2 (full; col-blocked layout has no row indexing)
    k_bspmm<<<NBKT, 256, 0, stream>>>(seg_ptr, edges, E_b, E_b, (float4*)E_a);
    k_gather_acc<<<(3 * BATCH * 16 + 255) / 256, 256, 0, stream>>>(
        bu, bp, bn, (const float4*)E_a, (float4*)out);
}